// Round 1
// baseline (519.985 us; speedup 1.0000x reference)
//
#include <hip/hip_runtime.h>
#include <math.h>

#define B_SZ 64
#define T_SZ 2048
#define EMB 512
#define ADIM 128
#define NFILT 32
#define KSZ 31
#define TT 64   // t-tile for align kernel

__device__ __forceinline__ float fast_tanh(float x) {
    // tanh(x) = 1 - 2/(exp(2x)+1); exp via v_exp_f32 path
    float e = __expf(2.f * x);
    return 1.f - 2.f / (e + 1.f);
}

// ---------------- Kernel A: processed query = h @ Wq^T  (B,128) ----------------
__global__ __launch_bounds__(128) void pq_kernel(const float* __restrict__ h,
                                                 const float* __restrict__ Wq,
                                                 float* __restrict__ pq) {
    const int b = blockIdx.x;
    const int d = threadIdx.x;
    __shared__ float hs[1024];
    for (int i = threadIdx.x; i < 1024; i += 128) hs[i] = h[b * 1024 + i];
    __syncthreads();
    const float4* wr = (const float4*)(Wq + (size_t)d * 1024);
    const float4* hr = (const float4*)hs;
    float acc = 0.f;
    #pragma unroll 8
    for (int k = 0; k < 256; ++k) {
        float4 w = wr[k], x = hr[k];
        acc += w.x * x.x + w.y * x.y + w.z * x.z + w.w * x.w;
    }
    pq[b * 128 + d] = acc;
}

// ---------------- Kernel B: fused conv + dense + tanh + dot -> alignment (B,T) ----------------
__global__ __launch_bounds__(256) void align_kernel(
    const float* __restrict__ aw_cat,    // (B,2,T)
    const float* __restrict__ pmem,      // (B,T,128)
    const float* __restrict__ pq,        // (B,128)
    const float* __restrict__ conv_w,    // (32,2,31)
    const float* __restrict__ W_dense,   // (128,32)
    const float* __restrict__ w_v,       // (128)
    const unsigned char* __restrict__ mask,  // (B,T) bool
    float* __restrict__ align_out)       // (B,T)
{
    const int b  = blockIdx.y;
    const int t0 = blockIdx.x * TT;
    const int tid = threadIdx.x;
    const int dq = tid & 31;   // d-quad index: covers d = dq*4 .. dq*4+3
    const int tg = tid >> 5;   // t-group 0..7 : covers t_local = tg*8 .. tg*8+7

    __shared__ float cw[NFILT * 62];          // conv weights (f)(c*31+k)
    __shared__ float wdT[NFILT * 132];        // W_dense transposed [f][d], pitch 132
    __shared__ float aw_s[2][TT + 40];        // staged aw_cat window with halo
    __shared__ float locT[NFILT][TT + 8];     // conv output transposed [f][t]

    for (int i = tid; i < NFILT * 62; i += 256) cw[i] = conv_w[i];
    for (int i = tid; i < 4096; i += 256) {
        int d = i >> 5, f = i & 31;
        wdT[f * 132 + d] = W_dense[i];
    }
    for (int i = tid; i < 2 * (TT + 40); i += 256) {
        int c = i / (TT + 40), x = i % (TT + 40);
        int t = t0 + x - 15;
        float v = 0.f;
        if (x < TT + 30 && t >= 0 && t < T_SZ)
            v = aw_cat[((size_t)b * 2 + c) * T_SZ + t];
        aw_s[c][x] = v;
    }
    __syncthreads();

    // ---- conv phase: thread (tg,dq) computes filter f=dq for t_local in [tg*8, tg*8+8)
    {
        float awr[2][40];
        #pragma unroll
        for (int c = 0; c < 2; ++c)
            #pragma unroll
            for (int q = 0; q < 10; ++q)
                *(float4*)&awr[c][q * 4] = *(const float4*)&aw_s[c][tg * 8 + q * 4];
        float cwr[62];
        #pragma unroll
        for (int q = 0; q < 31; ++q)
            *(float2*)&cwr[q * 2] = *(const float2*)&cw[dq * 62 + q * 2];
        float lres[8];
        #pragma unroll
        for (int j = 0; j < 8; ++j) {
            float acc = 0.f;
            #pragma unroll
            for (int k = 0; k < KSZ; ++k) {
                acc += awr[0][j + k] * cwr[k];
                acc += awr[1][j + k] * cwr[31 + k];
            }
            lres[j] = acc;
        }
        *(float4*)&locT[dq][tg * 8 + 0] = *(float4*)&lres[0];
        *(float4*)&locT[dq][tg * 8 + 4] = *(float4*)&lres[4];
    }
    __syncthreads();

    // ---- dense + energy phase: thread (tg,dq) computes d-quad dq for t_local in [tg*8, tg*8+8)
    const float4 pq4 = *(const float4*)&pq[b * 128 + dq * 4];
    const float4 wv4 = *(const float4*)&w_v[dq * 4];

    // prefetch pmem: 8 float4 per thread, coalesced across dq lanes
    float4 pm[2][4];
    const float4* pm4 = (const float4*)pmem;
    #pragma unroll
    for (int g = 0; g < 2; ++g)
        #pragma unroll
        for (int jj = 0; jj < 4; ++jj) {
            int tl = tg * 8 + g * 4 + jj;
            pm[g][jj] = pm4[((size_t)(b * T_SZ + t0 + tl)) * 32 + dq];
        }

    float4 acc[2][4];
    #pragma unroll
    for (int g = 0; g < 2; ++g)
        #pragma unroll
        for (int jj = 0; jj < 4; ++jj) acc[g][jj] = make_float4(0.f, 0.f, 0.f, 0.f);

    // two halves of f to bound register pressure (16 cached W columns at a time)
    #pragma unroll
    for (int h = 0; h < 2; ++h) {
        float4 wreg[16];
        #pragma unroll
        for (int f16 = 0; f16 < 16; ++f16)
            wreg[f16] = *(const float4*)&wdT[(h * 16 + f16) * 132 + dq * 4];
        #pragma unroll
        for (int g = 0; g < 2; ++g) {
            #pragma unroll
            for (int f16 = 0; f16 < 16; ++f16) {
                int f = h * 16 + f16;
                float4 lf = *(const float4*)&locT[f][tg * 8 + g * 4];  // broadcast read
                float4 w = wreg[f16];
                acc[g][0].x += lf.x * w.x; acc[g][0].y += lf.x * w.y; acc[g][0].z += lf.x * w.z; acc[g][0].w += lf.x * w.w;
                acc[g][1].x += lf.y * w.x; acc[g][1].y += lf.y * w.y; acc[g][1].z += lf.y * w.z; acc[g][1].w += lf.y * w.w;
                acc[g][2].x += lf.z * w.x; acc[g][2].y += lf.z * w.y; acc[g][2].z += lf.z * w.z; acc[g][2].w += lf.z * w.w;
                acc[g][3].x += lf.w * w.x; acc[g][3].y += lf.w * w.y; acc[g][3].z += lf.w * w.z; acc[g][3].w += lf.w * w.w;
            }
        }
    }

    // epilogue: tanh, dot with w_v, reduce across the 32 dq lanes
    #pragma unroll
    for (int g = 0; g < 2; ++g) {
        #pragma unroll
        for (int jj = 0; jj < 4; ++jj) {
            int tl = tg * 8 + g * 4 + jj;
            float4 a = acc[g][jj];
            float4 p = pm[g][jj];
            float ex = fast_tanh(pq4.x + a.x + p.x);
            float ey = fast_tanh(pq4.y + a.y + p.y);
            float ez = fast_tanh(pq4.z + a.z + p.z);
            float ew = fast_tanh(pq4.w + a.w + p.w);
            float part = ex * wv4.x + ey * wv4.y + ez * wv4.z + ew * wv4.w;
            #pragma unroll
            for (int off = 16; off; off >>= 1) part += __shfl_xor(part, off);
            if (dq == 0) {
                int t = t0 + tl;
                float av = part;
                if (mask[(size_t)b * T_SZ + t]) av = -INFINITY;
                align_out[(size_t)b * T_SZ + t] = av;
            }
        }
    }
}

// ---------------- Kernel C: in-place row softmax over T ----------------
__global__ __launch_bounds__(256) void softmax_kernel(float* __restrict__ a) {
    const int b = blockIdx.x;
    float* row = a + (size_t)b * T_SZ;
    const int tid = threadIdx.x;
    float v[8];
    #pragma unroll
    for (int i = 0; i < 8; ++i) v[i] = row[tid + 256 * i];
    float m = v[0];
    #pragma unroll
    for (int i = 1; i < 8; ++i) m = fmaxf(m, v[i]);
    #pragma unroll
    for (int off = 32; off; off >>= 1) m = fmaxf(m, __shfl_xor(m, off));
    __shared__ float sm[4];
    __shared__ float ss[4];
    const int wid = tid >> 6;
    if ((tid & 63) == 0) sm[wid] = m;
    __syncthreads();
    m = fmaxf(fmaxf(sm[0], sm[1]), fmaxf(sm[2], sm[3]));
    float e[8], s = 0.f;
    #pragma unroll
    for (int i = 0; i < 8; ++i) { e[i] = __expf(v[i] - m); s += e[i]; }
    #pragma unroll
    for (int off = 32; off; off >>= 1) s += __shfl_xor(s, off);
    if ((tid & 63) == 0) ss[wid] = s;
    __syncthreads();
    float inv = 1.f / (ss[0] + ss[1] + ss[2] + ss[3]);
    #pragma unroll
    for (int i = 0; i < 8; ++i) row[tid + 256 * i] = e[i] * inv;
}

// ---------------- Kernel D: context = weights @ memory  (B,512) ----------------
__global__ __launch_bounds__(256) void ctx_kernel(const float* __restrict__ mem,
                                                  const float* __restrict__ w,
                                                  float* __restrict__ out) {
    const int b = blockIdx.y;
    const int chunk = blockIdx.x;           // 0..31, each covers 64 t
    const int e4 = threadIdx.x & 127;       // float4 column over 512 emb
    const int tt = threadIdx.x >> 7;        // 0 or 1
    const float4* m4 = (const float4*)(mem + (size_t)b * T_SZ * EMB);
    const float* wr = w + (size_t)b * T_SZ;
    float4 acc = make_float4(0.f, 0.f, 0.f, 0.f);
    const int tb = chunk * 64;
    for (int j = tt; j < 64; j += 2) {
        const int t = tb + j;
        const float wt = wr[t];
        const float4 mm = m4[(size_t)t * 128 + e4];
        acc.x += wt * mm.x; acc.y += wt * mm.y; acc.z += wt * mm.z; acc.w += wt * mm.w;
    }
    __shared__ float4 red[128];
    if (tt) red[e4] = acc;
    __syncthreads();
    if (!tt) {
        const float4 o = red[e4];
        float* dst = out + (size_t)b * EMB + e4 * 4;
        atomicAdd(dst + 0, acc.x + o.x);
        atomicAdd(dst + 1, acc.y + o.y);
        atomicAdd(dst + 2, acc.z + o.z);
        atomicAdd(dst + 3, acc.w + o.w);
    }
}

extern "C" void kernel_launch(void* const* d_in, const int* in_sizes, int n_in,
                              void* d_out, int out_size, void* d_ws, size_t ws_size,
                              hipStream_t stream) {
    const float* h     = (const float*)d_in[0];   // (B,1024)
    const float* mem   = (const float*)d_in[1];   // (B,T,512)
    const float* pmem  = (const float*)d_in[2];   // (B,T,128)
    const float* awc   = (const float*)d_in[3];   // (B,2,T)
    const unsigned char* mask = (const unsigned char*)d_in[4];  // (B,T) bool
    const float* Wq    = (const float*)d_in[5];   // (128,1024)
    const float* cw    = (const float*)d_in[6];   // (32,2,31)
    const float* Wd    = (const float*)d_in[7];   // (128,32)
    const float* wv    = (const float*)d_in[8];   // (1,128)

    float* out = (float*)d_out;
    float* ctx = out;                      // (64,512)
    float* wts = out + B_SZ * EMB;         // (64,2048) — alignment, then softmaxed in place
    float* pq  = (float*)d_ws;             // (64,128) scratch

    hipMemsetAsync(ctx, 0, (size_t)B_SZ * EMB * sizeof(float), stream);
    pq_kernel<<<B_SZ, 128, 0, stream>>>(h, Wq, pq);
    align_kernel<<<dim3(T_SZ / TT, B_SZ), 256, 0, stream>>>(awc, pmem, pq, cw, Wd, wv, mask, wts);
    softmax_kernel<<<B_SZ, 256, 0, stream>>>(wts);
    ctx_kernel<<<dim3(T_SZ / 64, B_SZ), 256, 0, stream>>>(mem, wts, ctx);
}

// Round 4
// 469.637 us; speedup vs baseline: 1.1072x; 1.1072x over previous
//
#include <hip/hip_runtime.h>
#include <math.h>

#define B_SZ 64
#define T_SZ 2048
#define EMB 512
#define ADIM 128
#define NFILT 32
#define KSZ 31
#define TT 64   // t-tile for align kernel

typedef float f4v __attribute__((ext_vector_type(4)));

__device__ __forceinline__ float fast_tanh(float x) {
    float e = __expf(2.f * x);
    return 1.f - 2.f / (e + 1.f);
}

// ---------------- Kernel A: processed query = h @ Wq^T (B,128); also zeroes ctx ----------------
// grid (32 d-groups, 64 b), block 256 = 4 waves; wave w computes d = dg*4 + w
__global__ __launch_bounds__(256) void pq_kernel(const float* __restrict__ h,
                                                 const float* __restrict__ Wq,
                                                 float* __restrict__ pq,
                                                 float* __restrict__ ctx) {
    const int b = blockIdx.y, dg = blockIdx.x;
    const int w = threadIdx.x >> 6, lane = threadIdx.x & 63;
    // zero the context accumulator region (32 dg-blocks x 16 floats = 512 per b)
    if (threadIdx.x < 16) ctx[b * EMB + dg * 16 + threadIdx.x] = 0.f;
    const int d = dg * 4 + w;
    const float4* wr = (const float4*)(Wq + (size_t)d * 1024);
    const float4* hr = (const float4*)(h + (size_t)b * 1024);
    float acc = 0.f;
    #pragma unroll
    for (int it = 0; it < 4; ++it) {
        float4 a = wr[lane + 64 * it];
        float4 x = hr[lane + 64 * it];
        acc += a.x * x.x + a.y * x.y + a.z * x.z + a.w * x.w;
    }
    #pragma unroll
    for (int off = 32; off; off >>= 1) acc += __shfl_xor(acc, off);
    if (lane == 0) pq[b * 128 + d] = acc;
}

// ---------------- Kernel B: fused conv + dense + tanh + dot -> alignment (B,T) ----------------
__global__ __launch_bounds__(256) void align_kernel(
    const float* __restrict__ aw_cat,    // (B,2,T)
    const float* __restrict__ pmem,      // (B,T,128)
    const float* __restrict__ pq,        // (B,128)
    const float* __restrict__ conv_w,    // (32,2,31)
    const float* __restrict__ W_dense,   // (128,32)
    const float* __restrict__ w_v,       // (128)
    const unsigned char* __restrict__ mask,  // (B,T) bool
    float* __restrict__ align_out)       // (B,T)
{
    const int b  = blockIdx.y;
    const int t0 = blockIdx.x * TT;
    const int tid = threadIdx.x;
    const int dq = tid & 31;   // d-quad index: covers d = dq*4 .. dq*4+3
    const int tg = tid >> 5;   // t-group 0..7 : covers t_local = tg*8 .. tg*8+7

    __shared__ float cw[NFILT * 62];          // conv weights (f)(c*31+k)
    __shared__ float wdT[NFILT * 132];        // W_dense transposed [f][d], pitch 132
    __shared__ float aw_s[2][TT + 40];        // staged aw_cat window with halo
    __shared__ float locT[NFILT][TT + 8];     // conv output transposed [f][t]

    for (int i = tid; i < NFILT * 62; i += 256) cw[i] = conv_w[i];
    for (int i = tid; i < 4096; i += 256) {
        int d = i >> 5, f = i & 31;
        wdT[f * 132 + d] = W_dense[i];
    }
    for (int i = tid; i < 2 * (TT + 40); i += 256) {
        int c = i / (TT + 40), x = i % (TT + 40);
        int t = t0 + x - 15;
        float v = 0.f;
        if (x < TT + 30 && t >= 0 && t < T_SZ)
            v = aw_cat[((size_t)b * 2 + c) * T_SZ + t];
        aw_s[c][x] = v;
    }
    __syncthreads();

    // ---- conv phase: thread (tg,dq) computes filter f=dq for t_local in [tg*8, tg*8+8)
    {
        float awr[2][40];
        #pragma unroll
        for (int c = 0; c < 2; ++c)
            #pragma unroll
            for (int q = 0; q < 10; ++q)
                *(float4*)&awr[c][q * 4] = *(const float4*)&aw_s[c][tg * 8 + q * 4];
        float lres[8];
        #pragma unroll
        for (int j = 0; j < 8; ++j) lres[j] = 0.f;
        #pragma unroll
        for (int k = 0; k < KSZ; ++k) {
            float c0 = cw[dq * 62 + k];
            float c1 = cw[dq * 62 + 31 + k];
            #pragma unroll
            for (int j = 0; j < 8; ++j) {
                lres[j] += awr[0][j + k] * c0;
                lres[j] += awr[1][j + k] * c1;
            }
        }
        *(float4*)&locT[dq][tg * 8 + 0] = *(float4*)&lres[0];
        *(float4*)&locT[dq][tg * 8 + 4] = *(float4*)&lres[4];
    }
    __syncthreads();

    // ---- dense + energy phase: thread (tg,dq) computes d-quad dq for t_local in [tg*8, tg*8+8)
    const float4 pq4 = *(const float4*)&pq[b * 128 + dq * 4];
    const float4 wv4 = *(const float4*)&w_v[dq * 4];

    // prefetch pmem: 8 float4 per thread, coalesced across dq lanes
    float4 pm[2][4];
    const float4* pm4 = (const float4*)pmem;
    #pragma unroll
    for (int g = 0; g < 2; ++g)
        #pragma unroll
        for (int jj = 0; jj < 4; ++jj) {
            int tl = tg * 8 + g * 4 + jj;
            pm[g][jj] = pm4[((size_t)(b * T_SZ + t0 + tl)) * 32 + dq];
        }

    float4 acc[2][4];
    #pragma unroll
    for (int g = 0; g < 2; ++g)
        #pragma unroll
        for (int jj = 0; jj < 4; ++jj) acc[g][jj] = make_float4(0.f, 0.f, 0.f, 0.f);

    #pragma unroll
    for (int h = 0; h < 2; ++h) {
        float4 wreg[16];
        #pragma unroll
        for (int f16 = 0; f16 < 16; ++f16)
            wreg[f16] = *(const float4*)&wdT[(h * 16 + f16) * 132 + dq * 4];
        #pragma unroll
        for (int g = 0; g < 2; ++g) {
            #pragma unroll
            for (int f16 = 0; f16 < 16; ++f16) {
                int f = h * 16 + f16;
                float4 lf = *(const float4*)&locT[f][tg * 8 + g * 4];  // broadcast read
                float4 w = wreg[f16];
                acc[g][0].x += lf.x * w.x; acc[g][0].y += lf.x * w.y; acc[g][0].z += lf.x * w.z; acc[g][0].w += lf.x * w.w;
                acc[g][1].x += lf.y * w.x; acc[g][1].y += lf.y * w.y; acc[g][1].z += lf.y * w.z; acc[g][1].w += lf.y * w.w;
                acc[g][2].x += lf.z * w.x; acc[g][2].y += lf.z * w.y; acc[g][2].z += lf.z * w.z; acc[g][2].w += lf.z * w.w;
                acc[g][3].x += lf.w * w.x; acc[g][3].y += lf.w * w.y; acc[g][3].z += lf.w * w.z; acc[g][3].w += lf.w * w.w;
            }
        }
    }

    // epilogue: tanh, dot with w_v, reduce across the 32 dq lanes
    #pragma unroll
    for (int g = 0; g < 2; ++g) {
        #pragma unroll
        for (int jj = 0; jj < 4; ++jj) {
            int tl = tg * 8 + g * 4 + jj;
            float4 a = acc[g][jj];
            float4 p = pm[g][jj];
            float ex = fast_tanh(pq4.x + a.x + p.x);
            float ey = fast_tanh(pq4.y + a.y + p.y);
            float ez = fast_tanh(pq4.z + a.z + p.z);
            float ew = fast_tanh(pq4.w + a.w + p.w);
            float part = ex * wv4.x + ey * wv4.y + ez * wv4.z + ew * wv4.w;
            #pragma unroll
            for (int off = 16; off; off >>= 1) part += __shfl_xor(part, off);
            if (dq == 0) {
                int t = t0 + tl;
                float av = part;
                if (mask[(size_t)b * T_SZ + t]) av = -INFINITY;
                align_out[(size_t)b * T_SZ + t] = av;
            }
        }
    }
}

// ---------------- Kernel C: in-place row softmax over T ----------------
__global__ __launch_bounds__(256) void softmax_kernel(float* __restrict__ a) {
    const int b = blockIdx.x;
    float* row = a + (size_t)b * T_SZ;
    const int tid = threadIdx.x;
    float v[8];
    #pragma unroll
    for (int i = 0; i < 8; ++i) v[i] = row[tid + 256 * i];
    float m = v[0];
    #pragma unroll
    for (int i = 1; i < 8; ++i) m = fmaxf(m, v[i]);
    #pragma unroll
    for (int off = 32; off; off >>= 1) m = fmaxf(m, __shfl_xor(m, off));
    __shared__ float sm[4];
    __shared__ float ss[4];
    const int wid = tid >> 6;
    if ((tid & 63) == 0) sm[wid] = m;
    __syncthreads();
    m = fmaxf(fmaxf(sm[0], sm[1]), fmaxf(sm[2], sm[3]));
    float e[8], s = 0.f;
    #pragma unroll
    for (int i = 0; i < 8; ++i) { e[i] = __expf(v[i] - m); s += e[i]; }
    #pragma unroll
    for (int off = 32; off; off >>= 1) s += __shfl_xor(s, off);
    if ((tid & 63) == 0) ss[wid] = s;
    __syncthreads();
    float inv = 1.f / (ss[0] + ss[1] + ss[2] + ss[3]);
    #pragma unroll
    for (int i = 0; i < 8; ++i) row[tid + 256 * i] = e[i] * inv;
}

// ---------------- Kernel D: context = weights @ memory  (B,512) ----------------
__global__ __launch_bounds__(256) void ctx_kernel(const float* __restrict__ mem,
                                                  const float* __restrict__ w,
                                                  float* __restrict__ out) {
    const int b = blockIdx.y;
    const int chunk = blockIdx.x;           // 0..31, each covers 64 t
    const int e4 = threadIdx.x & 127;       // float4 column over 512 emb
    const int tt = threadIdx.x >> 7;        // 0 or 1
    const int tb = chunk * 64;

    __shared__ float ws_[64];
    if (threadIdx.x < 64) ws_[threadIdx.x] = w[(size_t)b * T_SZ + tb + threadIdx.x];
    __syncthreads();

    const f4v* m4 = (const f4v*)(mem + (size_t)b * T_SZ * EMB) + (size_t)tb * 128 + e4;
    f4v acc = (f4v){0.f, 0.f, 0.f, 0.f};
    #pragma unroll 8
    for (int j = tt; j < 64; j += 2) {
        f4v mm = __builtin_nontemporal_load(&m4[(size_t)j * 128]);
        float wt = ws_[j];
        acc += wt * mm;
    }

    __shared__ f4v red[128];
    if (tt) red[e4] = acc;
    __syncthreads();
    if (!tt) {
        f4v o = red[e4];
        float* dst = out + (size_t)b * EMB + e4 * 4;
        atomicAdd(dst + 0, acc.x + o.x);
        atomicAdd(dst + 1, acc.y + o.y);
        atomicAdd(dst + 2, acc.z + o.z);
        atomicAdd(dst + 3, acc.w + o.w);
    }
}

extern "C" void kernel_launch(void* const* d_in, const int* in_sizes, int n_in,
                              void* d_out, int out_size, void* d_ws, size_t ws_size,
                              hipStream_t stream) {
    const float* h     = (const float*)d_in[0];   // (B,1024)
    const float* mem   = (const float*)d_in[1];   // (B,T,512)
    const float* pmem  = (const float*)d_in[2];   // (B,T,128)
    const float* awc   = (const float*)d_in[3];   // (B,2,T)
    const unsigned char* mask = (const unsigned char*)d_in[4];  // (B,T) bool
    const float* Wq    = (const float*)d_in[5];   // (128,1024)
    const float* cw    = (const float*)d_in[6];   // (32,2,31)
    const float* Wd    = (const float*)d_in[7];   // (128,32)
    const float* wv    = (const float*)d_in[8];   // (1,128)

    float* out = (float*)d_out;
    float* ctx = out;                      // (64,512)
    float* wts = out + B_SZ * EMB;         // (64,2048) — alignment, then softmaxed in place
    float* pq  = (float*)d_ws;             // (64,128) scratch

    pq_kernel<<<dim3(32, B_SZ), 256, 0, stream>>>(h, Wq, pq, ctx);
    align_kernel<<<dim3(T_SZ / TT, B_SZ), 256, 0, stream>>>(awc, pmem, pq, cw, Wd, wv, mask, wts);
    softmax_kernel<<<B_SZ, 256, 0, stream>>>(wts);
    ctx_kernel<<<dim3(T_SZ / 64, B_SZ), 256, 0, stream>>>(mem, wts, ctx);
}

// Round 8
// 466.985 us; speedup vs baseline: 1.1135x; 1.0057x over previous
//
#include <hip/hip_runtime.h>
#include <math.h>

#define B_SZ 64
#define T_SZ 2048
#define EMB 512
#define ADIM 128
#define NFILT 32
#define KSZ 31
#define TT 64   // t-tile for align kernel

typedef float f4v __attribute__((ext_vector_type(4)));

__device__ __forceinline__ float fast_tanh(float x) {
    float e = __expf(2.f * x);
    return 1.f - 2.f / (e + 1.f);
}

// ---------------- Kernel A: processed query = h @ Wq^T (B,128); also zeroes ctx ----------------
// grid (32 d-groups, 64 b), block 256 = 4 waves; wave w computes d = dg*4 + w
__global__ __launch_bounds__(256) void pq_kernel(const float* __restrict__ h,
                                                 const float* __restrict__ Wq,
                                                 float* __restrict__ pq,
                                                 float* __restrict__ ctx) {
    const int b = blockIdx.y, dg = blockIdx.x;
    const int w = threadIdx.x >> 6, lane = threadIdx.x & 63;
    if (threadIdx.x < 16) ctx[b * EMB + dg * 16 + threadIdx.x] = 0.f;
    const int d = dg * 4 + w;
    const float4* wr = (const float4*)(Wq + (size_t)d * 1024);
    const float4* hr = (const float4*)(h + (size_t)b * 1024);
    float acc = 0.f;
    #pragma unroll
    for (int it = 0; it < 4; ++it) {
        float4 a = wr[lane + 64 * it];
        float4 x = hr[lane + 64 * it];
        acc += a.x * x.x + a.y * x.y + a.z * x.z + a.w * x.w;
    }
    #pragma unroll
    for (int off = 32; off; off >>= 1) acc += __shfl_xor(acc, off);
    if (lane == 0) pq[b * 128 + d] = acc;
}

// ---------------- Kernel B: fused conv + dense + tanh + dot -> alignment (B,T) ----------------
__global__ __launch_bounds__(256) void align_kernel(
    const float* __restrict__ aw_cat,    // (B,2,T)
    const float* __restrict__ pmem,      // (B,T,128)
    const float* __restrict__ pq,        // (B,128)
    const float* __restrict__ conv_w,    // (32,2,31)
    const float* __restrict__ W_dense,   // (128,32)
    const float* __restrict__ w_v,       // (128)
    const unsigned char* __restrict__ mask,  // (B,T) bool
    float* __restrict__ align_out)       // (B,T)
{
    const int b  = blockIdx.y;
    const int t0 = blockIdx.x * TT;
    const int tid = threadIdx.x;
    const int dq = tid & 31;   // d-quad index: covers d = dq*4 .. dq*4+3
    const int tg = tid >> 5;   // t-group 0..7 : covers t_local = tg*8 .. tg*8+7

    __shared__ float cw[NFILT * 62];          // conv weights (f)(c*31+k)
    __shared__ float wdT[NFILT * 132];        // W_dense transposed [f][d], pitch 132
    __shared__ float aw_s[2][TT + 40];        // staged aw_cat window with halo
    __shared__ float locT[NFILT][TT + 8];     // conv output transposed [f][t]

    for (int i = tid; i < NFILT * 62; i += 256) cw[i] = conv_w[i];
    for (int i = tid; i < 4096; i += 256) {
        int d = i >> 5, f = i & 31;
        wdT[f * 132 + d] = W_dense[i];
    }
    for (int i = tid; i < 2 * (TT + 40); i += 256) {
        int c = i / (TT + 40), x = i % (TT + 40);
        int t = t0 + x - 15;
        float v = 0.f;
        if (x < TT + 30 && t >= 0 && t < T_SZ)
            v = aw_cat[((size_t)b * 2 + c) * T_SZ + t];
        aw_s[c][x] = v;
    }
    __syncthreads();

    // ---- conv phase: thread (tg,dq) computes filter f=dq for t_local in [tg*8, tg*8+8)
    {
        float awr[2][40];
        #pragma unroll
        for (int c = 0; c < 2; ++c)
            #pragma unroll
            for (int q = 0; q < 10; ++q)
                *(float4*)&awr[c][q * 4] = *(const float4*)&aw_s[c][tg * 8 + q * 4];
        float lres[8];
        #pragma unroll
        for (int j = 0; j < 8; ++j) lres[j] = 0.f;
        #pragma unroll
        for (int k = 0; k < KSZ; ++k) {
            float c0 = cw[dq * 62 + k];
            float c1 = cw[dq * 62 + 31 + k];
            #pragma unroll
            for (int j = 0; j < 8; ++j) {
                lres[j] += awr[0][j + k] * c0;
                lres[j] += awr[1][j + k] * c1;
            }
        }
        *(float4*)&locT[dq][tg * 8 + 0] = *(float4*)&lres[0];
        *(float4*)&locT[dq][tg * 8 + 4] = *(float4*)&lres[4];
    }
    __syncthreads();

    // ---- dense + energy phase: thread (tg,dq) computes d-quad dq for t_local in [tg*8, tg*8+8)
    const float4 pq4 = *(const float4*)&pq[b * 128 + dq * 4];
    const float4 wv4 = *(const float4*)&w_v[dq * 4];

    float4 pm[2][4];
    const float4* pm4 = (const float4*)pmem;
    #pragma unroll
    for (int g = 0; g < 2; ++g)
        #pragma unroll
        for (int jj = 0; jj < 4; ++jj) {
            int tl = tg * 8 + g * 4 + jj;
            pm[g][jj] = pm4[((size_t)(b * T_SZ + t0 + tl)) * 32 + dq];
        }

    float4 acc[2][4];
    #pragma unroll
    for (int g = 0; g < 2; ++g)
        #pragma unroll
        for (int jj = 0; jj < 4; ++jj) acc[g][jj] = make_float4(0.f, 0.f, 0.f, 0.f);

    #pragma unroll
    for (int h = 0; h < 2; ++h) {
        float4 wreg[16];
        #pragma unroll
        for (int f16 = 0; f16 < 16; ++f16)
            wreg[f16] = *(const float4*)&wdT[(h * 16 + f16) * 132 + dq * 4];
        #pragma unroll
        for (int g = 0; g < 2; ++g) {
            #pragma unroll
            for (int f16 = 0; f16 < 16; ++f16) {
                int f = h * 16 + f16;
                float4 lf = *(const float4*)&locT[f][tg * 8 + g * 4];  // broadcast read
                float4 w = wreg[f16];
                acc[g][0].x += lf.x * w.x; acc[g][0].y += lf.x * w.y; acc[g][0].z += lf.x * w.z; acc[g][0].w += lf.x * w.w;
                acc[g][1].x += lf.y * w.x; acc[g][1].y += lf.y * w.y; acc[g][1].z += lf.y * w.z; acc[g][1].w += lf.y * w.w;
                acc[g][2].x += lf.z * w.x; acc[g][2].y += lf.z * w.y; acc[g][2].z += lf.z * w.z; acc[g][2].w += lf.z * w.w;
                acc[g][3].x += lf.w * w.x; acc[g][3].y += lf.w * w.y; acc[g][3].z += lf.w * w.z; acc[g][3].w += lf.w * w.w;
            }
        }
    }

    // epilogue: tanh, dot with w_v, reduce across the 32 dq lanes
    #pragma unroll
    for (int g = 0; g < 2; ++g) {
        #pragma unroll
        for (int jj = 0; jj < 4; ++jj) {
            int tl = tg * 8 + g * 4 + jj;
            float4 a = acc[g][jj];
            float4 p = pm[g][jj];
            float ex = fast_tanh(pq4.x + a.x + p.x);
            float ey = fast_tanh(pq4.y + a.y + p.y);
            float ez = fast_tanh(pq4.z + a.z + p.z);
            float ew = fast_tanh(pq4.w + a.w + p.w);
            float part = ex * wv4.x + ey * wv4.y + ez * wv4.z + ew * wv4.w;
            #pragma unroll
            for (int off = 16; off; off >>= 1) part += __shfl_xor(part, off);
            if (dq == 0) {
                int t = t0 + tl;
                float av = part;
                if (mask[(size_t)b * T_SZ + t]) av = -INFINITY;
                align_out[(size_t)b * T_SZ + t] = av;
            }
        }
    }
}

// ---------------- Kernel C: fused softmax + context ----------------
// grid (32 chunks, 64 b), block 256. Each block redundantly computes the row
// max/sum from the alignment (8 KB, L2-hot), writes its 64-weight segment to
// d_out, and accumulates its 64-t slice of the context via atomicAdd.
__global__ __launch_bounds__(256) void smctx_kernel(const float* __restrict__ mem,
                                                    const float* __restrict__ align,
                                                    float* __restrict__ wout,
                                                    float* __restrict__ ctx) {
    const int b = blockIdx.y;
    const int chunk = blockIdx.x;
    const int tid = threadIdx.x;
    const int tb = chunk * 64;
    const float* arow = align + (size_t)b * T_SZ;

    // --- row softmax stats (redundant per block) ---
    float4 v0 = ((const float4*)arow)[tid * 2 + 0];
    float4 v1 = ((const float4*)arow)[tid * 2 + 1];
    float m = fmaxf(fmaxf(fmaxf(v0.x, v0.y), fmaxf(v0.z, v0.w)),
                    fmaxf(fmaxf(v1.x, v1.y), fmaxf(v1.z, v1.w)));
    #pragma unroll
    for (int off = 32; off; off >>= 1) m = fmaxf(m, __shfl_xor(m, off));
    __shared__ float sm[4], ss[4];
    const int wid = tid >> 6;
    if ((tid & 63) == 0) sm[wid] = m;
    __syncthreads();
    m = fmaxf(fmaxf(sm[0], sm[1]), fmaxf(sm[2], sm[3]));
    float s = __expf(v0.x - m) + __expf(v0.y - m) + __expf(v0.z - m) + __expf(v0.w - m)
            + __expf(v1.x - m) + __expf(v1.y - m) + __expf(v1.z - m) + __expf(v1.w - m);
    #pragma unroll
    for (int off = 32; off; off >>= 1) s += __shfl_xor(s, off);
    if ((tid & 63) == 0) ss[wid] = s;
    __syncthreads();
    const float inv = 1.f / (ss[0] + ss[1] + ss[2] + ss[3]);

    // --- this block's 64 weights: held by threads tb/8 .. tb/8+7 ---
    __shared__ float ws_[64];
    const int base = tb >> 3;                 // first owning thread
    if (tid >= base && tid < base + 8) {
        const int o = (tid - base) * 8;       // offset within chunk
        float w0 = __expf(v0.x - m) * inv, w1 = __expf(v0.y - m) * inv;
        float w2 = __expf(v0.z - m) * inv, w3 = __expf(v0.w - m) * inv;
        float w4 = __expf(v1.x - m) * inv, w5 = __expf(v1.y - m) * inv;
        float w6 = __expf(v1.z - m) * inv, w7 = __expf(v1.w - m) * inv;
        ws_[o + 0] = w0; ws_[o + 1] = w1; ws_[o + 2] = w2; ws_[o + 3] = w3;
        ws_[o + 4] = w4; ws_[o + 5] = w5; ws_[o + 6] = w6; ws_[o + 7] = w7;
        float4* wo = (float4*)(wout + (size_t)b * T_SZ + tb + o);
        wo[0] = make_float4(w0, w1, w2, w3);
        wo[1] = make_float4(w4, w5, w6, w7);
    }
    __syncthreads();

    // --- context accumulation over this chunk's 64 t ---
    const int e4 = tid & 127;       // float4 column over 512 emb
    const int tt = tid >> 7;        // 0 or 1
    const f4v* m4 = (const f4v*)(mem + (size_t)b * T_SZ * EMB) + (size_t)tb * 128 + e4;
    f4v acc = (f4v){0.f, 0.f, 0.f, 0.f};
    #pragma unroll 8
    for (int j = tt; j < 64; j += 2) {
        f4v mm = __builtin_nontemporal_load(&m4[(size_t)j * 128]);
        acc += ws_[j] * mm;
    }
    __shared__ f4v red[128];
    if (tt) red[e4] = acc;
    __syncthreads();
    if (!tt) {
        f4v o = red[e4];
        float* dst = ctx + (size_t)b * EMB + e4 * 4;
        atomicAdd(dst + 0, acc.x + o.x);
        atomicAdd(dst + 1, acc.y + o.y);
        atomicAdd(dst + 2, acc.z + o.z);
        atomicAdd(dst + 3, acc.w + o.w);
    }
}

extern "C" void kernel_launch(void* const* d_in, const int* in_sizes, int n_in,
                              void* d_out, int out_size, void* d_ws, size_t ws_size,
                              hipStream_t stream) {
    const float* h     = (const float*)d_in[0];   // (B,1024)
    const float* mem   = (const float*)d_in[1];   // (B,T,512)
    const float* pmem  = (const float*)d_in[2];   // (B,T,128)
    const float* awc   = (const float*)d_in[3];   // (B,2,T)
    const unsigned char* mask = (const unsigned char*)d_in[4];  // (B,T) bool
    const float* Wq    = (const float*)d_in[5];   // (128,1024)
    const float* cw    = (const float*)d_in[6];   // (32,2,31)
    const float* Wd    = (const float*)d_in[7];   // (128,32)
    const float* wv    = (const float*)d_in[8];   // (1,128)

    float* out = (float*)d_out;
    float* ctx = out;                      // (64,512)
    float* wts = out + B_SZ * EMB;         // (64,2048) — alignment, then weights in place
    float* alg = (float*)d_ws;             // (64,2048) alignment scratch
    float* pq  = alg + B_SZ * T_SZ;        // (64,128) scratch

    pq_kernel<<<dim3(32, B_SZ), 256, 0, stream>>>(h, Wq, pq, ctx);
    align_kernel<<<dim3(T_SZ / TT, B_SZ), 256, 0, stream>>>(awc, pmem, pq, cw, Wd, wv, mask, alg);
    smctx_kernel<<<dim3(T_SZ / 64, B_SZ), 256, 0, stream>>>(mem, alg, wts, ctx);
}